// Round 10
// baseline (36.899 us; speedup 1.0000x reference)
//
#include <hip/hip_runtime.h>

// Problem geometry (fixed by reference setup_inputs)
#define B  4
#define D  48
#define H  128
#define W  240
#define H4 512   // 4*H
#define W4 960   // 4*W
#define DSPLIT 2           // threads per pixel in kernel 1
#define DPART  (D / DSPLIT)

// ===== R4 kernels verbatim (proven 23.7us). This round: launch k2 TWICE =====
// k2 is idempotent (pure function of disp4+spg), so the duplicate launch keeps
// output identical; dur_us - 23.7 isolates k2's warm marginal cost (+1 gap).

__global__ void __launch_bounds__(256)
topk_softargmax_kernel(const float* __restrict__ cost, float* __restrict__ disp4) {
    int gid = blockIdx.x * blockDim.x + threadIdx.x;
    const int nthreads = B * H * W * DSPLIT;
    if (gid >= nthreads) return;
    int pix  = gid >> 1;
    int half = gid & 1;
    int b    = pix / (H * W);
    int rem  = pix - b * (H * W);              // y*W + x
    const float* p = cost + (size_t)b * (D * H * W)
                          + (size_t)(half * DPART) * (H * W) + rem;

    float v[DPART];
    #pragma unroll
    for (int d = 0; d < DPART; ++d) v[d] = p[(size_t)d * (H * W)];

    float v1 = -INFINITY, v2 = -INFINITY;
    int   i1 = 0,          i2 = 0;
    const int d0 = half * DPART;
    #pragma unroll
    for (int d = 0; d < DPART; ++d) {
        float x = v[d];
        if (x > v1)      { v2 = v1; i2 = i1; v1 = x; i1 = d0 + d; }
        else if (x > v2) { v2 = x;  i2 = d0 + d; }
    }

    float pv1 = __shfl_xor(v1, 1);
    int   pi1 = __shfl_xor(i1, 1);
    float pv2 = __shfl_xor(v2, 1);
    int   pi2 = __shfl_xor(i2, 1);

    float av1, av2, bv1, bv2; int ai1, ai2, bi1, bi2;
    if (half == 0) { av1=v1;  ai1=i1;  av2=v2;  ai2=i2;  bv1=pv1; bi1=pi1; bv2=pv2; bi2=pi2; }
    else           { av1=pv1; ai1=pi1; av2=pv2; ai2=pi2; bv1=v1;  bi1=i1;  bv2=v2;  bi2=i2; }

    float t1v, t2v; int t1i, t2i;
    if (bv1 > av1) {
        t1v = bv1; t1i = bi1;
        if (av1 >= bv2) { t2v = av1; t2i = ai1; } else { t2v = bv2; t2i = bi2; }
    } else {
        t1v = av1; t1i = ai1;
        if (av2 >= bv1) { t2v = av2; t2i = ai2; } else { t2v = bv1; t2i = bi1; }
    }

    if (half == 0) {
        float e   = expf(t2v - t1v);
        disp4[pix] = ((float)t1i + (float)t2i * e) / (1.0f + e);
    }
}

__global__ void __launch_bounds__(256)
upfeat_kernel(const float* __restrict__ disp4, const float* __restrict__ spg,
              float* __restrict__ out) {
    int t = blockIdx.x * blockDim.x + threadIdx.x;
    const int nt = B * H4 * W;   // W = W4/4 thread-groups per row
    if (t >= nt) return;

    int xs  = t % W;
    int tmp = t / W;
    int Y   = tmp % H4;
    int b   = tmp / H4;
    int y   = Y >> 2;

    float dv[9];
    const float* dp = disp4 + (size_t)b * (H * W);
    #pragma unroll
    for (int dy = 0; dy < 3; ++dy) {
        int yy = y + dy - 1;
        #pragma unroll
        for (int dx = 0; dx < 3; ++dx) {
            int xx = xs + dx - 1;
            dv[dy * 3 + dx] = (yy >= 0 && yy < H && xx >= 0 && xx < W)
                              ? dp[yy * W + xx] : 0.0f;
        }
    }

    const float* sp = spg + (((size_t)b * 9) * H4 + Y) * W4 + 4 * xs;
    float4 acc = make_float4(0.f, 0.f, 0.f, 0.f);
    #pragma unroll
    for (int k = 0; k < 9; ++k) {
        float4 s = *reinterpret_cast<const float4*>(sp + (size_t)k * (H4 * W4));
        float  d = dv[k];
        acc.x += d * s.x; acc.y += d * s.y; acc.z += d * s.z; acc.w += d * s.w;
    }
    acc.x *= 4.f; acc.y *= 4.f; acc.z *= 4.f; acc.w *= 4.f;

    *reinterpret_cast<float4*>(out + ((size_t)b * H4 + Y) * W4 + 4 * xs) = acc;
}

extern "C" void kernel_launch(void* const* d_in, const int* in_sizes, int n_in,
                              void* d_out, int out_size, void* d_ws, size_t ws_size,
                              hipStream_t stream) {
    const float* cost = (const float*)d_in[0];   // [B,1,D,H,W]
    const float* spg  = (const float*)d_in[1];   // [B,9,H4,W4]
    float* outp  = (float*)d_out;                // [B,H4,W4]
    float* disp4 = (float*)d_ws;                 // [B,H,W] scratch (491 KB)

    {
        const int n = B * H * W * DSPLIT;        // 960 blocks
        topk_softargmax_kernel<<<(n + 255) / 256, 256, 0, stream>>>(cost, disp4);
    }
    {
        const int n = B * H4 * W;                // 1920 blocks
        upfeat_kernel<<<(n + 255) / 256, 256, 0, stream>>>(disp4, spg, outp);
        // DIAGNOSTIC duplicate: idempotent, output unchanged.
        // dur_us - 23.7 (R4 baseline) = t_k2(warm) + inter-dispatch gap.
        upfeat_kernel<<<(n + 255) / 256, 256, 0, stream>>>(disp4, spg, outp);
    }
}

// Round 11
// 26.904 us; speedup vs baseline: 1.3715x; 1.3715x over previous
//
#include <hip/hip_runtime.h>

// Problem geometry (fixed by reference setup_inputs)
#define B   4
#define D   48
#define H   128
#define W   240
#define H4  512   // 4*H
#define W4  960   // 4*W
#define HW  (H * W)
#define NPIX (B * HW)      // 122880
#define DQ  (D / 4)        // 12 d-slices per lane quarter

// Kernel 1: top-2 soft-argmax, float4 edition (R8 k1).
// Lane group of 4 owns 4 consecutive pixels; lane q holds d in [12q,12q+12).
// 12 float4 loads/thread, streaming top-2 per pixel, 2-step shfl_xor butterfly
// merge (lower lane = lower d range -> lowest-index tie-break preserved).
// VMEM issues: 1.47M float4 loads + 30K float4 stores (vs 5.9M scalar in R4).
__global__ void __launch_bounds__(256)
topk_softargmax_kernel(const float* __restrict__ cost, float* __restrict__ disp4) {
    int gid  = blockIdx.x * 256 + threadIdx.x;     // 0 .. NPIX-1
    int q    = gid & 3;                            // d-quarter
    int pix0 = (gid >> 2) * 4;                     // base pixel of the quad
    int b    = pix0 / HW;
    int rem  = pix0 - b * HW;
    const float* p = cost + (size_t)b * (D * HW) + (size_t)(q * DQ) * HW + rem;

    float4 vv[DQ];
    #pragma unroll
    for (int j = 0; j < DQ; ++j)
        vv[j] = *reinterpret_cast<const float4*>(p + (size_t)j * HW);

    float v1[4], v2[4]; int i1[4], i2[4];
    #pragma unroll
    for (int c = 0; c < 4; ++c) { v1[c] = -INFINITY; v2[c] = -INFINITY; i1[c] = 0; i2[c] = 0; }

    #pragma unroll
    for (int j = 0; j < DQ; ++j) {
        int d = q * DQ + j;
        float xs[4] = { vv[j].x, vv[j].y, vv[j].z, vv[j].w };
        #pragma unroll
        for (int c = 0; c < 4; ++c) {
            float x = xs[c];
            if (x > v1[c])      { v2[c] = v1[c]; i2[c] = i1[c]; v1[c] = x; i1[c] = d; }
            else if (x > v2[c]) { v2[c] = x;  i2[c] = d; }
        }
    }

    // butterfly merge across the 4-lane group (masks 1 then 2)
    #pragma unroll
    for (int step = 1; step <= 2; step <<= 1) {
        bool lower = (q & step) == 0;              // my list has the lower d range
        #pragma unroll
        for (int c = 0; c < 4; ++c) {
            float pv1 = __shfl_xor(v1[c], step);
            int   pi1 = __shfl_xor(i1[c], step);
            float pv2 = __shfl_xor(v2[c], step);
            int   pi2 = __shfl_xor(i2[c], step);
            float av1, av2, bv1, bv2; int ai1, ai2, bi1, bi2;
            if (lower) { av1=v1[c]; ai1=i1[c]; av2=v2[c]; ai2=i2[c]; bv1=pv1; bi1=pi1; bv2=pv2; bi2=pi2; }
            else       { av1=pv1;   ai1=pi1;   av2=pv2;   ai2=pi2;   bv1=v1[c]; bi1=i1[c]; bv2=v2[c]; bi2=i2[c]; }
            if (bv1 > av1) {        // top1 from high-d list
                v1[c] = bv1; i1[c] = bi1;
                if (av1 >= bv2) { v2[c] = av1; i2[c] = ai1; } else { v2[c] = bv2; i2[c] = bi2; }
            } else {                // ties -> low index
                v1[c] = av1; i1[c] = ai1;
                if (av2 >= bv1) { v2[c] = av2; i2[c] = ai2; } else { v2[c] = bv1; i2[c] = bi1; }
            }
        }
    }

    if (q == 0) {
        float4 r;
        { float e = expf(v2[0]-v1[0]); r.x = ((float)i1[0] + (float)i2[0]*e) / (1.0f+e); }
        { float e = expf(v2[1]-v1[1]); r.y = ((float)i1[1] + (float)i2[1]*e) / (1.0f+e); }
        { float e = expf(v2[2]-v1[2]); r.z = ((float)i1[2] + (float)i2[2]*e) / (1.0f+e); }
        { float e = expf(v2[3]-v1[3]); r.w = ((float)i1[3] + (float)i2[3]*e) / (1.0f+e); }
        *reinterpret_cast<float4*>(disp4 + pix0) = r;
    }
}

// Kernel 2: R4's proven upfeat (warm marginal cost measured ~12-13us = at-rate
// for its ~79 MB stream). One thread -> 4 consecutive fine pixels.
__global__ void __launch_bounds__(256)
upfeat_kernel(const float* __restrict__ disp4, const float* __restrict__ spg,
              float* __restrict__ out) {
    int t = blockIdx.x * blockDim.x + threadIdx.x;
    const int nt = B * H4 * (W4 / 4);
    if (t >= nt) return;

    int xs  = t % W;
    int tmp = t / W;
    int Y   = tmp % H4;
    int b   = tmp / H4;
    int y   = Y >> 2;

    float dv[9];
    const float* dp = disp4 + (size_t)b * HW;
    #pragma unroll
    for (int dy = 0; dy < 3; ++dy) {
        int yy = y + dy - 1;
        #pragma unroll
        for (int dx = 0; dx < 3; ++dx) {
            int xx = xs + dx - 1;
            dv[dy * 3 + dx] = (yy >= 0 && yy < H && xx >= 0 && xx < W)
                              ? dp[yy * W + xx] : 0.0f;
        }
    }

    const float* sp = spg + (((size_t)b * 9) * H4 + Y) * W4 + 4 * xs;
    float4 acc = make_float4(0.f, 0.f, 0.f, 0.f);
    #pragma unroll
    for (int k = 0; k < 9; ++k) {
        float4 s = *reinterpret_cast<const float4*>(sp + (size_t)k * (H4 * W4));
        float  d = dv[k];
        acc.x += d * s.x; acc.y += d * s.y; acc.z += d * s.z; acc.w += d * s.w;
    }
    acc.x *= 4.f; acc.y *= 4.f; acc.z *= 4.f; acc.w *= 4.f;

    *reinterpret_cast<float4*>(out + ((size_t)b * H4 + Y) * W4 + 4 * xs) = acc;
}

extern "C" void kernel_launch(void* const* d_in, const int* in_sizes, int n_in,
                              void* d_out, int out_size, void* d_ws, size_t ws_size,
                              hipStream_t stream) {
    const float* cost = (const float*)d_in[0];   // [B,1,D,H,W]
    const float* spg  = (const float*)d_in[1];   // [B,9,H4,W4]
    float* outp  = (float*)d_out;                // [B,H4,W4]
    float* disp4 = (float*)d_ws;                 // [B,H,W] scratch (491 KB)

    {
        const int n = NPIX;                      // 122880 threads, 480 blocks
        topk_softargmax_kernel<<<(n + 255) / 256, 256, 0, stream>>>(cost, disp4);
    }
    {
        const int n = B * H4 * (W4 / 4);         // 491520 threads, 1920 blocks
        upfeat_kernel<<<(n + 255) / 256, 256, 0, stream>>>(disp4, spg, outp);
    }
}